// Round 1
// baseline (9236.794 us; speedup 1.0000x reference)
//
#include <hip/hip_runtime.h>

typedef _Float16 f16;
typedef _Float16 f16x8 __attribute__((ext_vector_type(8)));
typedef float f32x4 __attribute__((ext_vector_type(4)));

#define TT 512
#define BB 512
#define DD 256
#define HH 512

// ws layout (bytes)
#define WPACK_BYTES (32*4*24*64*8*2)          // 3,145,728
#define HBUF_OFF    (WPACK_BYTES)             // 2 * 512*512 f16 = 1,048,576
#define READY_OFF   (HBUF_OFF + 2*BB*HH*2)    // 513*8 ints = 16,416
#define WS_NEEDED   (READY_OFF + 513*8*4)

__device__ __forceinline__ float sigf(float v) {
    return __frcp_rn(1.0f + __expf(-v));
}
__device__ __forceinline__ float tanh_fast(float v) {
    float e = __expf(2.0f * fminf(v, 15.0f));
    return 1.0f - 2.0f * __frcp_rn(e + 1.0f);
}

// Pre-pack W = [W_ih | W_hh] (f32) into per-block, per-fragment f16 layout:
// Wp[ji][nt][ks][lane][8]  with gate row g = nt*512 + ji*16 + (lane&15),
// k = ks*32 + (lane>>4)*8 + j  (k<256 -> W_ih, else W_hh).
__global__ void pack_w(const float* __restrict__ W_ih,
                       const float* __restrict__ W_hh,
                       f16* __restrict__ Wp) {
    int tid = blockIdx.x * 256 + threadIdx.x;   // 32*4*24*64 = 196608 total
    if (tid >= 32*4*24*64) return;
    int lane = tid & 63;
    int rest = tid >> 6;
    int ks   = rest % 24;
    int t3   = rest / 24;
    int nt   = t3 & 3;
    int ji   = t3 >> 2;
    int g  = nt*512 + ji*16 + (lane & 15);
    int k0 = ks*32 + ((lane >> 4) & 3)*8;
    const float* src = (k0 < 256) ? (W_ih + (size_t)g*DD + k0)
                                  : (W_hh + (size_t)g*HH + (k0 - 256));
    f16x8 v;
    #pragma unroll
    for (int j = 0; j < 8; ++j) v[j] = (f16)src[j];
    *(f16x8*)(Wp + (size_t)tid*8) = v;
}

// Persistent LSTM kernel: 256 blocks x 256 threads. block = (bi = blk&7, ji = blk>>3).
// Wave w handles batch m-tile w (16 batches). n-tiles 0..3 = gate types i,f,g,o.
__launch_bounds__(256, 1)
__global__ void lstm_fused(const float* __restrict__ x,
                           const float* __restrict__ b_ih,
                           const float* __restrict__ b_hh,
                           const float* __restrict__ W_fc,
                           const float* __restrict__ b_fc,
                           const f16* __restrict__ Wp,
                           f16* __restrict__ hbuf,
                           int* __restrict__ ready,
                           float* __restrict__ out) {
    extern __shared__ char smem[];
    f16x8* Wlds = (f16x8*)smem;          // [4][24][64] fragments, 96 KB

    const int tid  = threadIdx.x;
    const int lane = tid & 63;
    const int w    = tid >> 6;           // m-tile
    const int bi   = blockIdx.x & 7;
    const int ji   = blockIdx.x >> 3;

    // stationary W slice -> LDS (linear, coalesced)
    {
        const f16x8* src = (const f16x8*)Wp + (size_t)ji * (4*24*64);
        for (int i = tid; i < 4*24*64; i += 256) Wlds[i] = src[i];
    }
    const int u = lane & 15;
    float bias[4];
    #pragma unroll
    for (int nt = 0; nt < 4; ++nt)
        bias[nt] = b_ih[nt*512 + ji*16 + u] + b_hh[nt*512 + ji*16 + u];
    __syncthreads();

    const int arow = bi*64 + w*16 + (lane & 15);          // A-fragment row (batch)
    const float* xrow = x + (size_t)arow * TT * DD + ((lane >> 4)*8);
    const int hrow_off = arow * HH + ((lane >> 4)*8);
    const int ep_b = bi*64 + w*16 + ((lane >> 4)*4);      // epilogue batch base (+r)

    float c[4] = {0.f, 0.f, 0.f, 0.f};
    f32x4 acc[4];

    for (int s = 0; s < TT; ++s) {
        #pragma unroll
        for (int nt = 0; nt < 4; ++nt)
            acc[nt] = (f32x4){bias[nt], bias[nt], bias[nt], bias[nt]};

        // ---- x part (K 0..255), independent of h: runs before the wait ----
        const float* xs = xrow + (size_t)s * DD;
        #pragma unroll
        for (int ks = 0; ks < 8; ++ks) {
            float4 xa = *(const float4*)(xs + ks*32);
            float4 xb = *(const float4*)(xs + ks*32 + 4);
            f16x8 a;
            a[0]=(f16)xa.x; a[1]=(f16)xa.y; a[2]=(f16)xa.z; a[3]=(f16)xa.w;
            a[4]=(f16)xb.x; a[5]=(f16)xb.y; a[6]=(f16)xb.z; a[7]=(f16)xb.w;
            #pragma unroll
            for (int nt = 0; nt < 4; ++nt)
                acc[nt] = __builtin_amdgcn_mfma_f32_16x16x32_f16(
                    a, Wlds[(nt*24 + ks)*64 + lane], acc[nt], 0, 0, 0);
        }

        // ---- recurrent part (K 256..767) ----
        if (s > 0) {
            if (tid == 0) {
                while (__hip_atomic_load(&ready[s*8 + bi], __ATOMIC_RELAXED,
                                         __HIP_MEMORY_SCOPE_AGENT) < 32)
                    __builtin_amdgcn_s_sleep(2);
            }
            __syncthreads();
            __builtin_amdgcn_fence(__ATOMIC_ACQUIRE, "agent");
            const f16* hsrc = hbuf + (size_t)(s & 1) * BB * HH;
            #pragma unroll 4
            for (int ks = 8; ks < 24; ++ks) {
                f16x8 a = *(const f16x8*)(hsrc + hrow_off + (ks - 8)*32);
                #pragma unroll
                for (int nt = 0; nt < 4; ++nt)
                    acc[nt] = __builtin_amdgcn_mfma_f32_16x16x32_f16(
                        a, Wlds[(nt*24 + ks)*64 + lane], acc[nt], 0, 0, 0);
            }
        }

        // ---- LSTM cell: lane holds i,f,g,o for (batch ep_b+r, unit ji*16+u) ----
        f16* hdst = hbuf + (size_t)((s + 1) & 1) * BB * HH + (size_t)ep_b * HH + ji*16 + u;
        #pragma unroll
        for (int r = 0; r < 4; ++r) {
            float ig = sigf(acc[0][r]);
            float fg = sigf(acc[1][r]);
            float gg = tanh_fast(acc[2][r]);
            float og = sigf(acc[3][r]);
            c[r] = fg * c[r] + ig * gg;
            float h = og * tanh_fast(c[r]);
            hdst[(size_t)r * HH] = (f16)h;
        }
        __syncthreads();   // drains all waves' h stores (vmcnt 0 before barrier)
        if (tid == 0) {
            __builtin_amdgcn_fence(__ATOMIC_RELEASE, "agent");
            __hip_atomic_fetch_add(&ready[(s + 1)*8 + bi], 1, __ATOMIC_RELAXED,
                                   __HIP_MEMORY_SCOPE_AGENT);
        }
    }

    // ---- classifier head: one block per batch-chunk (ji == 0) ----
    if (ji == 0) {
        if (tid == 0) {
            while (__hip_atomic_load(&ready[TT*8 + bi], __ATOMIC_RELAXED,
                                     __HIP_MEMORY_SCOPE_AGENT) < 32)
                __builtin_amdgcn_s_sleep(2);
        }
        __syncthreads();
        __builtin_amdgcn_fence(__ATOMIC_ACQUIRE, "agent");
        const f16* hT = hbuf + (size_t)(TT & 1) * BB * HH;   // h_512 lives in buf 0
        float* red = (float*)smem;                            // reuse LDS
        int b_local = tid >> 2, seg = tid & 3;
        const f16* hr = hT + (size_t)(bi*64 + b_local) * HH + seg*128;
        const float* wf = W_fc + seg*128;
        float ssum = 0.f;
        for (int k = 0; k < 128; ++k) ssum += (float)hr[k] * wf[k];
        red[b_local*4 + seg] = ssum;
        __syncthreads();
        if (tid < 64) {
            float v = red[tid*4+0] + red[tid*4+1] + red[tid*4+2] + red[tid*4+3] + b_fc[0];
            out[bi*64 + tid] = sigf(v);
        }
    }
}

extern "C" void kernel_launch(void* const* d_in, const int* in_sizes, int n_in,
                              void* d_out, int out_size, void* d_ws, size_t ws_size,
                              hipStream_t stream) {
    const float* x    = (const float*)d_in[0];
    const float* W_ih = (const float*)d_in[1];
    const float* W_hh = (const float*)d_in[2];
    const float* b_ih = (const float*)d_in[3];
    const float* b_hh = (const float*)d_in[4];
    const float* W_fc = (const float*)d_in[5];
    const float* b_fc = (const float*)d_in[6];
    float* out = (float*)d_out;

    f16* Wp    = (f16*)d_ws;
    f16* hbuf  = (f16*)((char*)d_ws + HBUF_OFF);
    int* ready = (int*)((char*)d_ws + READY_OFF);

    hipMemsetAsync(ready, 0, 513*8*4, stream);
    pack_w<<<768, 256, 0, stream>>>(W_ih, W_hh, Wp);

    static bool attr_set = []() {
        hipFuncSetAttribute(reinterpret_cast<const void*>(lstm_fused),
                            hipFuncAttributeMaxDynamicSharedMemorySize, 98304);
        return true;
    }();
    (void)attr_set;

    void* kargs[] = {(void*)&x, (void*)&b_ih, (void*)&b_hh, (void*)&W_fc,
                     (void*)&b_fc, (void*)&Wp, (void*)&hbuf, (void*)&ready,
                     (void*)&out};
    hipLaunchCooperativeKernel(reinterpret_cast<const void*>(lstm_fused),
                               dim3(256), dim3(256), kargs, 98304, stream);
}

// Round 2
// 4590.886 us; speedup vs baseline: 2.0120x; 2.0120x over previous
//
#include <hip/hip_runtime.h>

typedef _Float16 f16;
typedef _Float16 f16x8 __attribute__((ext_vector_type(8)));
typedef float f32x4 __attribute__((ext_vector_type(4)));
typedef unsigned int u32;
typedef unsigned long long u64;

#define TT 512
#define BB 512
#define DD 256
#define HH 512

// ws layout (bytes)
#define WPACK_BYTES (32*4*24*64*8*2)          // 3,145,728
#define HBUF_OFF    (WPACK_BYTES)             // 2 * 512*512 f16 = 1,048,576
#define FLAG_OFF    (HBUF_OFF + 2*BB*HH*2)
#define NFLAGS      ((TT+1)*8*4*32)           // 525,312 u32 = 2,101,248 B

__device__ __forceinline__ float sigf(float v) {
    return __frcp_rn(1.0f + __expf(-v));
}
__device__ __forceinline__ float tanh_fast(float v) {
    float e = __expf(2.0f * fminf(v, 15.0f));
    return 1.0f - 2.0f * __frcp_rn(e + 1.0f);
}

// Pre-pack W = [W_ih | W_hh] (f32) into per-block, per-fragment f16 layout:
// Wp[ji][nt][ks][lane][8]  with gate row g = nt*512 + ji*16 + (lane&15),
// k = ks*32 + (lane>>4)*8 + j  (k<256 -> W_ih, else W_hh).
// (Same fragment serves as the MFMA *A* operand after the operand swap:
//  A-frag m-index = lane&15 = gate row, k = (lane>>4)*8+j.)
__global__ void pack_w(const float* __restrict__ W_ih,
                       const float* __restrict__ W_hh,
                       f16* __restrict__ Wp) {
    int tid = blockIdx.x * 256 + threadIdx.x;   // 32*4*24*64 = 196608 total
    if (tid >= 32*4*24*64) return;
    int lane = tid & 63;
    int rest = tid >> 6;
    int ks   = rest % 24;
    int t3   = rest / 24;
    int nt   = t3 & 3;
    int ji   = t3 >> 2;
    int g  = nt*512 + ji*16 + (lane & 15);
    int k0 = ks*32 + ((lane >> 4) & 3)*8;
    const float* src = (k0 < 256) ? (W_ih + (size_t)g*DD + k0)
                                  : (W_hh + (size_t)g*HH + (k0 - 256));
    f16x8 v;
    #pragma unroll
    for (int j = 0; j < 8; ++j) v[j] = (f16)src[j];
    *(f16x8*)(Wp + (size_t)tid*8) = v;
}

// Persistent LSTM kernel: 256 blocks x 256 threads. block = (bi = blk&7, ji = blk>>3).
// MFMA roles: A = W (m = 16 gate rows of gate-type nt), B = [x;h] (n = 16 batches).
// C/D: row (lane>>4)*4+r = unit-in-tile, col lane&15 = batch-in-tile
//   -> each lane owns (one batch) x (4 consecutive units) for all 4 gates:
//      cell update is lane-local, h store is one contiguous 8B atomic.
// Sync: per-wave domains (bi, w): 32 producer waves (ji = 0..31); per-producer
// flag words; agent-scope relaxed atomics for h + flags; NO fences, NO barriers
// in the step loop.
__launch_bounds__(256, 1)
__global__ void lstm_fused(const float* __restrict__ x,
                           const float* __restrict__ b_ih,
                           const float* __restrict__ b_hh,
                           const float* __restrict__ W_fc,
                           const float* __restrict__ b_fc,
                           const f16* __restrict__ Wp,
                           f16* __restrict__ hbuf,
                           u32* __restrict__ flags,
                           float* __restrict__ out) {
    extern __shared__ char smem[];
    f16x8* Wlds = (f16x8*)smem;          // [4][24][64] fragments, 96 KB

    const int tid  = threadIdx.x;
    const int lane = tid & 63;
    const int w    = tid >> 6;           // batch n-tile within group
    const int bi   = blockIdx.x & 7;
    const int ji   = blockIdx.x >> 3;

    // stationary W slice -> LDS (linear, coalesced)
    {
        const f16x8* src = (const f16x8*)Wp + (size_t)ji * (4*24*64);
        for (int i = tid; i < 4*24*64; i += 256) Wlds[i] = src[i];
    }

    const int uq = (lane >> 4) * 4;      // unit quad within ji's 16 units
    float bias[4][4];
    #pragma unroll
    for (int nt = 0; nt < 4; ++nt)
        #pragma unroll
        for (int r = 0; r < 4; ++r)
            bias[nt][r] = b_ih[nt*512 + ji*16 + uq + r] + b_hh[nt*512 + ji*16 + uq + r];
    __syncthreads();                     // Wlds ready (only barrier before head)

    const int batch  = bi*64 + w*16 + (lane & 15);
    const int koff   = (lane >> 4) * 8;
    const float* xrow = x + (size_t)batch * TT * DD + koff;
    u64* hq = (u64*)hbuf;
    const int hrow_q = (batch * HH + koff) >> 2;                // u64 index
    u64* hdst0 = hq + ((batch * HH + ji*16 + uq) >> 2);

    float c[4] = {0.f, 0.f, 0.f, 0.f};
    f32x4 acc[4];

    for (int s = 0; s < TT; ++s) {
        #pragma unroll
        for (int nt = 0; nt < 4; ++nt)
            acc[nt] = (f32x4){bias[nt][0], bias[nt][1], bias[nt][2], bias[nt][3]};

        // ---- x part (K 0..255): loads issue first, latency hides under
        //      the producer tail / flag propagation ----
        const float* xs = xrow + (size_t)s * DD;
        #pragma unroll
        for (int ks = 0; ks < 8; ++ks) {
            float4 xa = *(const float4*)(xs + ks*32);
            float4 xb = *(const float4*)(xs + ks*32 + 4);
            f16x8 a;
            a[0]=(f16)xa.x; a[1]=(f16)xa.y; a[2]=(f16)xa.z; a[3]=(f16)xa.w;
            a[4]=(f16)xb.x; a[5]=(f16)xb.y; a[6]=(f16)xb.z; a[7]=(f16)xb.w;
            #pragma unroll
            for (int nt = 0; nt < 4; ++nt)
                acc[nt] = __builtin_amdgcn_mfma_f32_16x16x32_f16(
                    Wlds[(nt*24 + ks)*64 + lane], a, acc[nt], 0, 0, 0);
        }

        // ---- recurrent part (K 256..767) ----
        if (s > 0) {
            // wave-parallel poll: 32 producers of my (bi, w) domain,
            // one coalesced 128B flag-line load per round
            const u32* f = flags + (((size_t)s*8 + bi)*4 + w)*32;
            for (;;) {
                u32 v = 1u;
                if (lane < 32)
                    v = __hip_atomic_load(&f[lane], __ATOMIC_RELAXED,
                                          __HIP_MEMORY_SCOPE_AGENT);
                if (__all(v != 0)) break;
                __builtin_amdgcn_s_sleep(1);
            }
            asm volatile("" ::: "memory");   // compiler ordering: no h-load hoist

            const size_t pbase = (size_t)(s & 1) * (BB*HH/4);
            #pragma unroll 4
            for (int ks = 8; ks < 24; ++ks) {
                union { u64 q[2]; f16x8 v; } A;
                size_t qi = pbase + hrow_q + (size_t)(ks - 8) * 8;
                A.q[0] = __hip_atomic_load(hq + qi,     __ATOMIC_RELAXED,
                                           __HIP_MEMORY_SCOPE_AGENT);
                A.q[1] = __hip_atomic_load(hq + qi + 1, __ATOMIC_RELAXED,
                                           __HIP_MEMORY_SCOPE_AGENT);
                #pragma unroll
                for (int nt = 0; nt < 4; ++nt)
                    acc[nt] = __builtin_amdgcn_mfma_f32_16x16x32_f16(
                        Wlds[(nt*24 + ks)*64 + lane], A.v, acc[nt], 0, 0, 0);
            }
        }

        // ---- cell: lane = (batch, units uq..uq+3) for all 4 gates ----
        union { u64 q; f16 h4[4]; } H;
        #pragma unroll
        for (int r = 0; r < 4; ++r) {
            float ig = sigf(acc[0][r]);
            float fg = sigf(acc[1][r]);
            float gg = tanh_fast(acc[2][r]);
            float og = sigf(acc[3][r]);
            c[r] = fg * c[r] + ig * gg;
            H.h4[r] = (f16)(og * tanh_fast(c[r]));
        }
        __hip_atomic_store(hdst0 + (size_t)((s + 1) & 1) * (BB*HH/4), H.q,
                           __ATOMIC_RELAXED, __HIP_MEMORY_SCOPE_AGENT);
        // wave-local release: h stores complete at coherence point, THEN flag
        asm volatile("s_waitcnt vmcnt(0)" ::: "memory");
        if (lane == 0)
            __hip_atomic_store(&flags[(((size_t)(s + 1)*8 + bi)*4 + w)*32 + ji],
                               1u, __ATOMIC_RELAXED, __HIP_MEMORY_SCOPE_AGENT);
    }

    // ---- classifier head: blocks with ji == 0, one per batch group ----
    if (ji == 0) {
        {
            const u32* f = flags + (((size_t)TT*8 + bi)*4 + w)*32;
            for (;;) {
                u32 v = 1u;
                if (lane < 32)
                    v = __hip_atomic_load(&f[lane], __ATOMIC_RELAXED,
                                          __HIP_MEMORY_SCOPE_AGENT);
                if (__all(v != 0)) break;
                __builtin_amdgcn_s_sleep(1);
            }
        }
        asm volatile("" ::: "memory");
        __syncthreads();   // all 4 waves' domains ready -> all 64 batches ready
        const u64* hT = hq + (size_t)(TT & 1) * (BB*HH/4);
        float* red = (float*)smem;       // W no longer needed
        int b_local = tid >> 2, seg = tid & 3;
        const u64* hr = hT + (((size_t)(bi*64 + b_local) * HH + seg*128) >> 2);
        const float* wf = W_fc + seg*128;
        float ssum = 0.f;
        for (int kq = 0; kq < 32; ++kq) {
            union { u64 q; f16 h4[4]; } Hv;
            Hv.q = __hip_atomic_load(hr + kq, __ATOMIC_RELAXED,
                                     __HIP_MEMORY_SCOPE_AGENT);
            #pragma unroll
            for (int j = 0; j < 4; ++j) ssum += (float)Hv.h4[j] * wf[kq*4 + j];
        }
        red[b_local*4 + seg] = ssum;
        __syncthreads();
        if (tid < 64) {
            float v = red[tid*4+0] + red[tid*4+1] + red[tid*4+2] + red[tid*4+3] + b_fc[0];
            out[bi*64 + tid] = sigf(v);
        }
    }
}

extern "C" void kernel_launch(void* const* d_in, const int* in_sizes, int n_in,
                              void* d_out, int out_size, void* d_ws, size_t ws_size,
                              hipStream_t stream) {
    const float* x    = (const float*)d_in[0];
    const float* W_ih = (const float*)d_in[1];
    const float* W_hh = (const float*)d_in[2];
    const float* b_ih = (const float*)d_in[3];
    const float* b_hh = (const float*)d_in[4];
    const float* W_fc = (const float*)d_in[5];
    const float* b_fc = (const float*)d_in[6];
    float* out = (float*)d_out;

    f16* Wp    = (f16*)d_ws;
    f16* hbuf  = (f16*)((char*)d_ws + HBUF_OFF);
    u32* flags = (u32*)((char*)d_ws + FLAG_OFF);

    hipMemsetAsync(flags, 0, NFLAGS * sizeof(u32), stream);
    pack_w<<<768, 256, 0, stream>>>(W_ih, W_hh, Wp);

    static bool attr_set = []() {
        hipFuncSetAttribute(reinterpret_cast<const void*>(lstm_fused),
                            hipFuncAttributeMaxDynamicSharedMemorySize, 98304);
        return true;
    }();
    (void)attr_set;

    void* kargs[] = {(void*)&x, (void*)&b_ih, (void*)&b_hh, (void*)&W_fc,
                     (void*)&b_fc, (void*)&Wp, (void*)&hbuf, (void*)&flags,
                     (void*)&out};
    hipLaunchCooperativeKernel(reinterpret_cast<const void*>(lstm_fused),
                               dim3(256), dim3(256), kargs, 98304, stream);
}

// Round 3
// 3457.613 us; speedup vs baseline: 2.6714x; 1.3278x over previous
//
#include <hip/hip_runtime.h>

typedef _Float16 f16;
typedef _Float16 f16x8 __attribute__((ext_vector_type(8)));
typedef float f32x4 __attribute__((ext_vector_type(4)));
typedef unsigned int u32;
typedef unsigned long long u64;

#define TT 512
#define BB 512
#define DD 256
#define HH 512

// ws layout (bytes)
#define WPACK_BYTES (32*4*24*64*8*2)          // 3,145,728
#define HBUF_OFF    (WPACK_BYTES)             // 2 * 512*512 f16 = 1,048,576
#define FLAG_OFF    (HBUF_OFF + 2*BB*HH*2)
#define NFLAGS      ((TT+1)*8*4*32)           // 525,312 u32

__device__ __forceinline__ float sigf(float v) {
    return __frcp_rn(1.0f + __expf(-v));
}
__device__ __forceinline__ float tanh_fast(float v) {
    float e = __expf(2.0f * fminf(v, 15.0f));
    return 1.0f - 2.0f * __frcp_rn(e + 1.0f);
}

// Pre-pack W = [W_ih | W_hh] (f32) into per-block, per-fragment f16 layout:
// Wp[ji][nt][ks][lane][8]  with gate row g = nt*512 + ji*16 + (lane&15),
// k = ks*32 + (lane>>4)*8 + j  (k<256 -> W_ih, else W_hh).
__global__ void pack_w(const float* __restrict__ W_ih,
                       const float* __restrict__ W_hh,
                       f16* __restrict__ Wp) {
    int tid = blockIdx.x * 256 + threadIdx.x;   // 32*4*24*64 = 196608 total
    if (tid >= 32*4*24*64) return;
    int lane = tid & 63;
    int rest = tid >> 6;
    int ks   = rest % 24;
    int t3   = rest / 24;
    int nt   = t3 & 3;
    int ji   = t3 >> 2;
    int g  = nt*512 + ji*16 + (lane & 15);
    int k0 = ks*32 + ((lane >> 4) & 3)*8;
    const float* src = (k0 < 256) ? (W_ih + (size_t)g*DD + k0)
                                  : (W_hh + (size_t)g*HH + (k0 - 256));
    f16x8 v;
    #pragma unroll
    for (int j = 0; j < 8; ++j) v[j] = (f16)src[j];
    *(f16x8*)(Wp + (size_t)tid*8) = v;
}

// Persistent LSTM kernel: 256 blocks x 256 threads. block = (bi = blk&7, ji = blk>>3).
// MFMA roles: A = W (m = 16 gate rows of gate-type nt), B = [x;h] (n = 16 batches).
// Software pipeline: acc carries bias + x(s)*W_ih computed in the PREVIOUS
// iteration's tail; x(s+1) loads issue before the poll; x-MFMA tail covers the
// h-store ack latency before the release vmcnt(0).
__launch_bounds__(256, 1)
__global__ void lstm_fused(const float* __restrict__ x,
                           const float* __restrict__ b_ih,
                           const float* __restrict__ b_hh,
                           const float* __restrict__ W_fc,
                           const float* __restrict__ b_fc,
                           const f16* __restrict__ Wp,
                           f16* __restrict__ hbuf,
                           u32* __restrict__ flags,
                           float* __restrict__ out) {
    extern __shared__ char smem[];
    f16x8* Wlds = (f16x8*)smem;          // [4][24][64] fragments, 96 KB

    const int tid  = threadIdx.x;
    const int lane = tid & 63;
    const int w    = tid >> 6;           // batch n-tile within group
    const int bi   = blockIdx.x & 7;
    const int ji   = blockIdx.x >> 3;

    {
        const f16x8* src = (const f16x8*)Wp + (size_t)ji * (4*24*64);
        for (int i = tid; i < 4*24*64; i += 256) Wlds[i] = src[i];
    }

    const int uq = (lane >> 4) * 4;      // unit quad within ji's 16 units
    float bias[4][4];
    #pragma unroll
    for (int nt = 0; nt < 4; ++nt)
        #pragma unroll
        for (int r = 0; r < 4; ++r)
            bias[nt][r] = b_ih[nt*512 + ji*16 + uq + r] + b_hh[nt*512 + ji*16 + uq + r];
    __syncthreads();                     // Wlds ready

    const int batch  = bi*64 + w*16 + (lane & 15);
    const int koff   = (lane >> 4) * 8;
    const float* xrow = x + (size_t)batch * TT * DD + koff;
    u64* hq = (u64*)hbuf;
    const int hrow_q = (batch * HH + koff) >> 2;                // u64 index
    u64* hdst0 = hq + ((batch * HH + ji*16 + uq) >> 2);

    float c[4] = {0.f, 0.f, 0.f, 0.f};
    f32x4 acc[4];

    // ---- prologue: acc = bias + x(0) * W_ih ----
    {
        float4 xa[8], xb[8];
        #pragma unroll
        for (int ks = 0; ks < 8; ++ks) {
            xa[ks] = *(const float4*)(xrow + ks*32);
            xb[ks] = *(const float4*)(xrow + ks*32 + 4);
        }
        #pragma unroll
        for (int nt = 0; nt < 4; ++nt)
            acc[nt] = (f32x4){bias[nt][0], bias[nt][1], bias[nt][2], bias[nt][3]};
        #pragma unroll
        for (int ks = 0; ks < 8; ++ks) {
            f16x8 a;
            a[0]=(f16)xa[ks].x; a[1]=(f16)xa[ks].y; a[2]=(f16)xa[ks].z; a[3]=(f16)xa[ks].w;
            a[4]=(f16)xb[ks].x; a[5]=(f16)xb[ks].y; a[6]=(f16)xb[ks].z; a[7]=(f16)xb[ks].w;
            #pragma unroll
            for (int nt = 0; nt < 4; ++nt)
                acc[nt] = __builtin_amdgcn_mfma_f32_16x16x32_f16(
                    Wlds[(nt*24 + ks)*64 + lane], a, acc[nt], 0, 0, 0);
        }
    }

    for (int s = 0; s < TT; ++s) {
        // ---- 1. issue x(s+1) raw loads: latency hides under poll ----
        float4 na[8], nb[8];
        const bool havex = (s + 1 < TT);
        if (havex) {
            const float* xs = xrow + (size_t)(s + 1) * DD;
            #pragma unroll
            for (int ks = 0; ks < 8; ++ks) {
                na[ks] = *(const float4*)(xs + ks*32);
                nb[ks] = *(const float4*)(xs + ks*32 + 4);
            }
        }

        // ---- 2. recurrent part: poll, bulk h loads, 64 MFMA ----
        if (s > 0) {
            const u32* f = flags + (((size_t)s*8 + bi)*4 + w)*32;
            for (;;) {
                u32 v = 1u;
                if (lane < 32)
                    v = __hip_atomic_load(&f[lane], __ATOMIC_RELAXED,
                                          __HIP_MEMORY_SCOPE_AGENT);
                if (__all(v != 0)) break;
                __builtin_amdgcn_s_sleep(1);
            }
            asm volatile("" ::: "memory");   // no h-load hoist above poll

            const size_t pbase = (size_t)(s & 1) * (BB*HH/4);
            union HU { u64 q[2]; f16x8 v; };
            HU A[16];
            #pragma unroll
            for (int ks = 0; ks < 16; ++ks) {
                size_t qi = pbase + hrow_q + (size_t)ks * 8;
                A[ks].q[0] = __hip_atomic_load(hq + qi,     __ATOMIC_RELAXED,
                                               __HIP_MEMORY_SCOPE_AGENT);
                A[ks].q[1] = __hip_atomic_load(hq + qi + 1, __ATOMIC_RELAXED,
                                               __HIP_MEMORY_SCOPE_AGENT);
            }
            #pragma unroll
            for (int ks = 0; ks < 16; ++ks)
                #pragma unroll
                for (int nt = 0; nt < 4; ++nt)
                    acc[nt] = __builtin_amdgcn_mfma_f32_16x16x32_f16(
                        Wlds[(nt*24 + ks + 8)*64 + lane], A[ks].v, acc[nt], 0, 0, 0);
        }

        // ---- 3. cell: lane = (batch, units uq..uq+3) for all 4 gates ----
        union { u64 q; f16 h4[4]; } H;
        #pragma unroll
        for (int r = 0; r < 4; ++r) {
            float ig = sigf(acc[0][r]);
            float fg = sigf(acc[1][r]);
            float gg = tanh_fast(acc[2][r]);
            float og = sigf(acc[3][r]);
            c[r] = fg * c[r] + ig * gg;
            H.h4[r] = (f16)(og * tanh_fast(c[r]));
        }
        __hip_atomic_store(hdst0 + (size_t)((s + 1) & 1) * (BB*HH/4), H.q,
                           __ATOMIC_RELAXED, __HIP_MEMORY_SCOPE_AGENT);

        // ---- 4. tail: rebuild acc = bias + x(s+1)*W_ih (covers store ack) ----
        if (havex) {
            #pragma unroll
            for (int nt = 0; nt < 4; ++nt)
                acc[nt] = (f32x4){bias[nt][0], bias[nt][1], bias[nt][2], bias[nt][3]};
            #pragma unroll
            for (int ks = 0; ks < 8; ++ks) {
                f16x8 a;
                a[0]=(f16)na[ks].x; a[1]=(f16)na[ks].y; a[2]=(f16)na[ks].z; a[3]=(f16)na[ks].w;
                a[4]=(f16)nb[ks].x; a[5]=(f16)nb[ks].y; a[6]=(f16)nb[ks].z; a[7]=(f16)nb[ks].w;
                #pragma unroll
                for (int nt = 0; nt < 4; ++nt)
                    acc[nt] = __builtin_amdgcn_mfma_f32_16x16x32_f16(
                        Wlds[(nt*24 + ks)*64 + lane], a, acc[nt], 0, 0, 0);
            }
        }

        // ---- 5. release: h store at coherence point, then flag ----
        asm volatile("s_waitcnt vmcnt(0)" ::: "memory");
        if (lane == 0)
            __hip_atomic_store(&flags[(((size_t)(s + 1)*8 + bi)*4 + w)*32 + ji],
                               1u, __ATOMIC_RELAXED, __HIP_MEMORY_SCOPE_AGENT);
    }

    // ---- classifier head: blocks with ji == 0, one per batch group ----
    if (ji == 0) {
        {
            const u32* f = flags + (((size_t)TT*8 + bi)*4 + w)*32;
            for (;;) {
                u32 v = 1u;
                if (lane < 32)
                    v = __hip_atomic_load(&f[lane], __ATOMIC_RELAXED,
                                          __HIP_MEMORY_SCOPE_AGENT);
                if (__all(v != 0)) break;
                __builtin_amdgcn_s_sleep(1);
            }
        }
        asm volatile("" ::: "memory");
        __syncthreads();   // all 4 waves' domains ready -> all 64 batches ready
        const u64* hT = hq + (size_t)(TT & 1) * (BB*HH/4);
        float* red = (float*)smem;       // W no longer needed
        int b_local = tid >> 2, seg = tid & 3;
        const u64* hr = hT + (((size_t)(bi*64 + b_local) * HH + seg*128) >> 2);
        const float* wf = W_fc + seg*128;
        float ssum = 0.f;
        for (int kq = 0; kq < 32; ++kq) {
            union { u64 q; f16 h4[4]; } Hv;
            Hv.q = __hip_atomic_load(hr + kq, __ATOMIC_RELAXED,
                                     __HIP_MEMORY_SCOPE_AGENT);
            #pragma unroll
            for (int j = 0; j < 4; ++j) ssum += (float)Hv.h4[j] * wf[kq*4 + j];
        }
        red[b_local*4 + seg] = ssum;
        __syncthreads();
        if (tid < 64) {
            float v = red[tid*4+0] + red[tid*4+1] + red[tid*4+2] + red[tid*4+3] + b_fc[0];
            out[bi*64 + tid] = sigf(v);
        }
    }
}

extern "C" void kernel_launch(void* const* d_in, const int* in_sizes, int n_in,
                              void* d_out, int out_size, void* d_ws, size_t ws_size,
                              hipStream_t stream) {
    const float* x    = (const float*)d_in[0];
    const float* W_ih = (const float*)d_in[1];
    const float* W_hh = (const float*)d_in[2];
    const float* b_ih = (const float*)d_in[3];
    const float* b_hh = (const float*)d_in[4];
    const float* W_fc = (const float*)d_in[5];
    const float* b_fc = (const float*)d_in[6];
    float* out = (float*)d_out;

    f16* Wp    = (f16*)d_ws;
    f16* hbuf  = (f16*)((char*)d_ws + HBUF_OFF);
    u32* flags = (u32*)((char*)d_ws + FLAG_OFF);

    hipMemsetAsync(flags, 0, NFLAGS * sizeof(u32), stream);
    pack_w<<<768, 256, 0, stream>>>(W_ih, W_hh, Wp);

    static bool attr_set = []() {
        hipFuncSetAttribute(reinterpret_cast<const void*>(lstm_fused),
                            hipFuncAttributeMaxDynamicSharedMemorySize, 98304);
        return true;
    }();
    (void)attr_set;

    void* kargs[] = {(void*)&x, (void*)&b_ih, (void*)&b_hh, (void*)&W_fc,
                     (void*)&b_fc, (void*)&Wp, (void*)&hbuf, (void*)&flags,
                     (void*)&out};
    hipLaunchCooperativeKernel(reinterpret_cast<const void*>(lstm_fused),
                               dim3(256), dim3(256), kargs, 98304, stream);
}